// Round 3
// baseline (525.365 us; speedup 1.0000x reference)
//
#include <hip/hip_runtime.h>
#include <math.h>

#define NZ 10
#define NLENS 29
#define NPAIR 45
#define NUNIT 23

static __device__ __forceinline__ float2 cmulf(float2 a, float2 b){
    return make_float2(a.x*b.x - a.y*b.y, a.x*b.y + a.y*b.x);
}
#define SW(i) ((i) ^ (((i)>>5)&31))
#define WB() __builtin_amdgcn_wave_barrier()

static constexpr double PI2   = 6.283185307179586;
static constexpr double KD    = PI2/0.00051;            // 2*pi/lambda
static constexpr double F0D   = 1.0/(2.0*(3.6/1024.0)); // 1/(2*PS)
static constexpr double FSTEP = 2.0*F0D/1023.0;
static constexpr double IL2D  = (1.0/0.00051)*(1.0/0.00051);
static constexpr double TPPID = PI2*8.74;               // 2*pi*T_PROP

// load swizzled twiddle table from global (coalesced), then one block barrier
static __device__ __forceinline__ void load_W(float2* W, const float2* Wg, int tid){
    for (int t = tid; t < 1024; t += 256) W[SW(t)] = Wg[t];
}

template<bool INV>
static __device__ __forceinline__ void bf4(const float2 a[4], float2 w1, float2 w2, float2 w3, float2 o[4]){
    if (INV){ w1.y = -w1.y; w2.y = -w2.y; w3.y = -w3.y; }
    float2 a1 = cmulf(a[1], w1), a2 = cmulf(a[2], w2), a3 = cmulf(a[3], w3);
    float2 t0 = make_float2(a[0].x+a2.x, a[0].y+a2.y);
    float2 t1 = make_float2(a[0].x-a2.x, a[0].y-a2.y);
    float2 t2 = make_float2(a1.x+a3.x, a1.y+a3.y);
    float2 t3 = make_float2(a1.x-a3.x, a1.y-a3.y);
    o[0] = make_float2(t0.x+t2.x, t0.y+t2.y);
    o[2] = make_float2(t0.x-t2.x, t0.y-t2.y);
    if (!INV){
        o[1] = make_float2(t1.x + t3.y, t1.y - t3.x);
        o[3] = make_float2(t1.x - t3.y, t1.y + t3.x);
    } else {
        o[1] = make_float2(t1.x - t3.y, t1.y + t3.x);
        o[3] = make_float2(t1.x + t3.y, t1.y - t3.x);
    }
}
template<bool INV>
static __device__ __forceinline__ void bf4nt(const float2 a[4], float2 o[4]){
    float2 t0 = make_float2(a[0].x+a[2].x, a[0].y+a[2].y);
    float2 t1 = make_float2(a[0].x-a[2].x, a[0].y-a[2].y);
    float2 t2 = make_float2(a[1].x+a[3].x, a[1].y+a[3].y);
    float2 t3 = make_float2(a[1].x-a[3].x, a[1].y-a[3].y);
    o[0] = make_float2(t0.x+t2.x, t0.y+t2.y);
    o[2] = make_float2(t0.x-t2.x, t0.y-t2.y);
    if (!INV){
        o[1] = make_float2(t1.x + t3.y, t1.y - t3.x);
        o[3] = make_float2(t1.x - t3.y, t1.y + t3.x);
    } else {
        o[1] = make_float2(t1.x - t3.y, t1.y + t3.x);
        o[3] = make_float2(t1.x + t3.y, t1.y - t3.x);
    }
}

// ===== radix-16 (two fused radix-4 stages) 1024-pt Stockham, ONE WAVE per FFT =====
// LDS slice B (1024 float2, SW-swizzled) is private to the wave -> wave_barrier only.
static __device__ __forceinline__ void r16_load(const float2* B, int t, float2 a[4][4]){
    #pragma unroll
    for (int k = 0; k < 4; ++k)
        #pragma unroll
        for (int q = 0; q < 4; ++q)
            a[k][q] = B[SW(t + 64*k + 256*q)];
}
template<bool INV>
static __device__ __forceinline__ void r16_s14(const float2 a[4][4], const float2* W, float2 z[4][4]){
    float2 y[4][4];
    #pragma unroll
    for (int k = 0; k < 4; ++k) bf4nt<INV>(a[k], y[k]);
    #pragma unroll
    for (int i = 0; i < 4; ++i){
        float2 b[4] = { y[0][i], y[1][i], y[2][i], y[3][i] };
        bf4<INV>(b, W[SW(64*i)], W[SW(128*i)], W[SW(192*i)], z[i]);
    }
}
static __device__ __forceinline__ void r16_st1(float2* B, int t, const float2 z[4][4]){
    #pragma unroll
    for (int i = 0; i < 4; ++i)
        #pragma unroll
        for (int d = 0; d < 4; ++d)
            B[SW(16*t + i + 4*d)] = z[i][d];
}
template<bool INV>
static __device__ __forceinline__ void r16_s16_64(const float2 a[4][4], const float2* W, int t, float2 z[4][4]){
    int mt = t & 15;
    float2 y[4][4];
    float2 w1 = W[SW(16*mt)], w2 = W[SW(32*mt)], w3 = W[SW(48*mt)];
    #pragma unroll
    for (int k = 0; k < 4; ++k) bf4<INV>(a[k], w1, w2, w3, y[k]);
    #pragma unroll
    for (int n = 0; n < 4; ++n){
        int m2 = mt + 16*n;
        float2 b[4] = { y[0][n], y[1][n], y[2][n], y[3][n] };
        bf4<INV>(b, W[SW(4*m2)], W[SW(8*m2)], W[SW(12*m2)], z[n]);
    }
}
static __device__ __forceinline__ void r16_st2(float2* B, int t, const float2 z[4][4]){
    int base = 256*(t>>4) + (t&15);
    #pragma unroll
    for (int n = 0; n < 4; ++n)
        #pragma unroll
        for (int d = 0; d < 4; ++d)
            B[SW(base + 16*n + 64*d)] = z[n][d];
}
template<bool INV>
static __device__ __forceinline__ void r16_s256(const float2 a[4][4], const float2* W, int t, float2 z[4][4]){
    #pragma unroll
    for (int k = 0; k < 4; ++k){
        int j = t + 64*k;
        bf4<INV>(a[k], W[SW(j)], W[SW(2*j)], W[SW(3*j)], z[k]);
    }
}
static __device__ __forceinline__ void r16_st3(float2* B, int t, const float2 z[4][4]){
    #pragma unroll
    for (int k = 0; k < 4; ++k)
        #pragma unroll
        for (int d = 0; d < 4; ++d)
            B[SW(t + 64*k + 256*d)] = z[k][d];
}
// FFT with input in registers (a[k][q] = element t+64k+256q), output in z (element t+64k+256d)
template<bool INV>
static __device__ void r16_fft_regs(float2* B, const float2* W, int t, float2 a[4][4], float2 z[4][4]){
    float2 b[4][4];
    r16_s14<INV>(a, W, z);
    WB(); r16_st1(B, t, z); WB();
    r16_load(B, t, b); r16_s16_64<INV>(b, W, t, z);
    WB(); r16_st2(B, t, z); WB();
    r16_load(B, t, b); r16_s256<INV>(b, W, t, z);
}
// FFT with input already staged in the wave's LDS slice
template<bool INV>
static __device__ void r16_fft_lds(float2* B, const float2* W, int t, float2 z[4][4]){
    float2 a[4][4];
    r16_load(B, t, a);
    r16_fft_regs<INV>(B, W, t, a, z);
}

static __device__ __forceinline__ float2 expi_from_double(double ph){
    double t = ph * (1.0/PI2);
    t -= floor(t);
    float th = (float)(t * PI2);
    float s, c; sincosf(th, &s, &c);
    return make_float2(c, s);
}

// ---- merged prep: lens phase+aperture, H table, transposed (tF,mask), twiddles ----
__global__ __launch_bounds__(256) void k_prep(const float* __restrict__ rlist,
        const float* __restrict__ xpos, const float* __restrict__ ypos,
        const float* __restrict__ tF, const float* __restrict__ dm,
        float2* __restrict__ phiA, float2* __restrict__ HT,
        float2* __restrict__ TM, float2* __restrict__ Wg){
    __shared__ float2 T[32][33];
    int b = blockIdx.x, tid = threadIdx.x;
    if (b < 4096){
        int idx = b*256 + tid;
        int r = idx >> 10, c = idx & 1023;
        float x = (float)(-1.8 + c*(3.6/1023.0));
        float y = (float)(-1.8 + r*(3.6/1023.0));
        const float ca2 = (float)(0.165*0.165);
        float Ts = 0.f; int any = 0;
        for (int l = 0; l < NLENS; ++l){
            float dx = x - xpos[l], dy = y - ypos[l];
            float d2 = dx*dx + dy*dy;
            if (d2 <= ca2){
                float rr = rlist[l];
                Ts += rr - sqrtf(fmaxf(rr*rr - d2, 1e-12f));
                any = 1;
            }
        }
        float ap = (any && (x*x + y*y) <= 0.81f) ? 1.f : 0.f;
        float phi = (float)(KD*(1.515 - 1.0)) * Ts;
        phiA[idx] = make_float2(phi, ap);
    } else if (b < 8192){
        int idx = (b-4096)*256 + tid;
        int c = idx >> 10, r = idx & 1023;
        int cs = (c + 512) & 1023, rs = (r + 512) & 1023;
        float fc = (float)(-F0D + cs*FSTEP);
        float fr = (float)(-F0D + rs*FSTEP);
        float kz2 = __fsub_rn(__fsub_rn((float)IL2D, __fmul_rn(fc,fc)), __fmul_rn(fr,fr));
        float kzf = sqrtf(fmaxf(kz2, 0.f));
        float phf = __fmul_rn((float)TPPID, kzf);
        HT[idx] = expi_from_double((double)phf);
    } else if (b < 9216){
        int tb = b - 8192;
        int bx = tb & 31, by = tb >> 5;
        int tx = tid & 31, ty = tid >> 5;   // 32 x 8
        #pragma unroll
        for (int j = 0; j < 4; ++j){
            int r = by*32 + ty + 8*j, c = bx*32 + tx;
            T[ty+8*j][tx] = make_float2(tF[(size_t)r*1024 + c], dm[(size_t)r*1024 + c]);
        }
        __syncthreads();
        #pragma unroll
        for (int j = 0; j < 4; ++j){
            int c = bx*32 + ty + 8*j, r = by*32 + tx;
            TM[(size_t)c*1024 + r] = T[tx][ty+8*j];
        }
    } else {
        int t = (b-9216)*256 + tid;
        float a = (float)((double)t * (-PI2/1024.0));
        float s, c; sincosf(a, &s, &c);
        Wg[t] = make_float2(c, s);
    }
}

// ---- P1 (row, 4 waves = 4 rows/block): generate U1, fwd row FFT ----
__global__ __launch_bounds__(256) void k_p1(const float2* __restrict__ phiA,
        const float* __restrict__ defocus, float2* __restrict__ S,
        const float2* __restrict__ Wg){
    __shared__ float2 buf[4*1024];
    __shared__ float2 W[1024];
    int tid = threadIdx.x, zz = blockIdx.y;
    load_W(W, Wg, tid);
    __syncthreads();
    int w = tid >> 6, t = tid & 63;
    int row = blockIdx.x*4 + w;
    float2* B = buf + w*1024;
    float zf = defocus[zz];
    float y  = (float)(-1.8 + row*(3.6/1023.0));
    const float KF = (float)KD;
    const float2* pha = phiA + ((size_t)row << 10);
    float2 a[4][4], z[4][4];
    #pragma unroll
    for (int k = 0; k < 4; ++k)
        #pragma unroll
        for (int q = 0; q < 4; ++q){
            int idx = t + 64*k + 256*q;
            float x = (float)(-1.8 + idx*(3.6/1023.0));
            float2 pa = pha[idx];
            float2 u  = make_float2(0.f, 0.f);
            if (pa.y != 0.f){
                float qq     = x*x + y*y;
                float phi_in = (KF*qq) / (2.0f*zf);
                u = expi_from_double((double)(phi_in + pa.x));
            }
            a[k][q] = u;
        }
    r16_fft_regs<false>(B, W, t, a, z);
    float2* Srow = S + ((size_t)zz << 20) + ((size_t)row << 10);
    #pragma unroll
    for (int k = 0; k < 4; ++k)
        #pragma unroll
        for (int d = 0; d < 4; ++d)
            Srow[t + 64*k + 256*d] = z[k][d];
}

// ---- P2 (col): fwd col FFT, *H (regs), inv col FFT, in place ----
__global__ __launch_bounds__(256) void k_p2(float2* __restrict__ S,
        const float2* __restrict__ HT, const float2* __restrict__ Wg){
    __shared__ float2 buf[4*1024];
    __shared__ float2 W[1024];
    int tid = threadIdx.x, bx = blockIdx.x, zz = blockIdx.y;
    int cb = ((bx & 7) << 5) | (bx >> 3);
    int c0 = cb*4;
    load_W(W, Wg, tid);
    float2* Sz = S + ((size_t)zz << 20);
    for (int it = 0; it < 16; ++it){
        int rr = it*64 + (tid>>2), cc = tid & 3;
        buf[cc*1024 + SW(rr)] = Sz[((size_t)rr << 10) + c0 + cc];
    }
    __syncthreads();
    int col = tid >> 6, t = tid & 63;
    float2* B = buf + col*1024;
    float2 z[4][4], a[4][4];
    r16_fft_lds<false>(B, W, t, z);
    const float2* Hc = HT + ((size_t)(c0+col) << 10);
    #pragma unroll
    for (int k = 0; k < 4; ++k)
        #pragma unroll
        for (int d = 0; d < 4; ++d)
            z[k][d] = cmulf(z[k][d], Hc[t + 64*k + 256*d]);
    r16_fft_regs<true>(B, W, t, z, a);
    const float sc = 1.0f/1024.0f;
    #pragma unroll
    for (int k = 0; k < 4; ++k)
        #pragma unroll
        for (int d = 0; d < 4; ++d){ a[k][d].x *= sc; a[k][d].y *= sc; }
    WB();
    r16_st3(B, t, a);
    __syncthreads();
    for (int it = 0; it < 16; ++it){
        int rr = it*64 + (tid>>2), cc = tid & 3;
        Sz[((size_t)rr << 10) + c0 + cc] = buf[cc*1024 + SW(rr)];
    }
}

// ---- P3 (row): inv row FFT -> p=|u|^2, row sums, fwd row FFT of p ----
__global__ __launch_bounds__(256) void k_p3(float2* __restrict__ S,
        float* __restrict__ sumPart, const float2* __restrict__ Wg){
    __shared__ float2 buf[4*1024];
    __shared__ float2 W[1024];
    int tid = threadIdx.x, zz = blockIdx.y;
    load_W(W, Wg, tid);
    __syncthreads();
    int w = tid >> 6, t = tid & 63;
    int row = blockIdx.x*4 + w;
    float2* B = buf + w*1024;
    float2* Srow = S + ((size_t)zz << 20) + ((size_t)row << 10);
    float2 a[4][4], z[4][4];
    #pragma unroll
    for (int k = 0; k < 4; ++k)
        #pragma unroll
        for (int q = 0; q < 4; ++q)
            a[k][q] = Srow[t + 64*k + 256*q];
    r16_fft_regs<true>(B, W, t, a, z);
    const float s2 = (1.0f/1024.0f)*(1.0f/1024.0f);
    float lsum = 0.f;
    #pragma unroll
    for (int k = 0; k < 4; ++k)
        #pragma unroll
        for (int d = 0; d < 4; ++d){
            float2 u = z[k][d];
            float p = (u.x*u.x + u.y*u.y) * s2;
            a[k][d] = make_float2(p, 0.f);
            lsum += p;
        }
    for (int o = 32; o > 0; o >>= 1) lsum += __shfl_down(lsum, o, 64);
    if (t == 0) sumPart[zz*1024 + row] = lsum;
    WB();
    r16_fft_regs<false>(B, W, t, a, z);
    #pragma unroll
    for (int k = 0; k < 4; ++k)
        #pragma unroll
        for (int d = 0; d < 4; ++d)
            Srow[t + 64*k + 256*d] = z[k][d];
}

// ---- P4 (col): fwd col FFT, scale 1/sum, masked diag partials; S updated ----
__global__ __launch_bounds__(256) void k_p4(float2* __restrict__ S,
        const float* __restrict__ sumPart, const float2* __restrict__ TM,
        float* __restrict__ dpart, const float2* __restrict__ Wg){
    __shared__ float2 buf[4*1024];
    __shared__ float2 W[1024];
    int tid = threadIdx.x, bx = blockIdx.x, zz = blockIdx.y;
    int cb = ((bx & 7) << 5) | (bx >> 3);
    int c0 = cb*4;
    load_W(W, Wg, tid);
    float2* Sz = S + ((size_t)zz << 20);
    for (int it = 0; it < 16; ++it){
        int rr = it*64 + (tid>>2), cc = tid & 3;
        buf[cc*1024 + SW(rr)] = Sz[((size_t)rr << 10) + c0 + cc];
    }
    // per-wave redundant total-sum reduction (no extra barrier needed)
    int col = tid >> 6, t = tid & 63;
    double sd = 0.0;
    for (int i = t; i < 1024; i += 64) sd += (double)sumPart[zz*1024 + i];
    for (int o = 32; o > 0; o >>= 1) sd += __shfl_down(sd, o, 64);
    sd = __shfl(sd, 0, 64);
    float inv = (float)(1.0/sd);
    __syncthreads();
    float2* B = buf + col*1024;
    float2 z[4][4];
    r16_fft_lds<false>(B, W, t, z);
    const float2* TMc = TM + ((size_t)(c0+col) << 10);
    const float nrm = 1.0f/1048576.0f;
    float dacc = 0.f;
    #pragma unroll
    for (int k = 0; k < 4; ++k)
        #pragma unroll
        for (int d = 0; d < 4; ++d){
            float2 s = z[k][d]; s.x *= inv; s.y *= inv; z[k][d] = s;
            float2 tm = TMc[t + 64*k + 256*d];
            float dff = (s.x*s.x + s.y*s.y - tm.x) * nrm;
            dacc += tm.y * dff * dff;
        }
    for (int o = 32; o > 0; o >>= 1) dacc += __shfl_down(dacc, o, 64);
    WB();
    r16_st3(B, t, z);
    __syncthreads();            // all FFT + W reads done; safe to reuse W slots
    if (t == 0) ((float*)W)[col] = dacc;
    for (int it = 0; it < 16; ++it){
        int rr = it*64 + (tid>>2), cc = tid & 3;
        Sz[((size_t)rr << 10) + c0 + cc] = buf[cc*1024 + SW(rr)];
    }
    __syncthreads();
    if (tid == 0){
        float* r = (float*)W;
        dpart[zz*256 + cb] = r[0]+r[1]+r[2]+r[3];
    }
}

static __device__ __forceinline__ void pair_of(int p, int& a, int& b){
    int i = 0, c = NZ-1;
    while (p >= c){ p -= c; ++i; --c; }
    a = i; b = i + 1 + p;
}

// ---- pairA (row): Z = conj(Si1)Sj1 + i*conj(Si2)Sj2, inv row FFT -> U ----
__global__ __launch_bounds__(256) void k_pairA(const float2* __restrict__ S,
        float2* __restrict__ U, int ubase, const float2* __restrict__ Wg){
    __shared__ float2 buf[4*1024];
    __shared__ float2 W[1024];
    int tid = threadIdx.x, ug = blockIdx.y;
    load_W(W, Wg, tid);
    __syncthreads();
    int w = tid >> 6, t = tid & 63;
    int row = blockIdx.x*4 + w;
    float2* B = buf + w*1024;
    int u = ubase + ug;
    int pa = 2*u, pb = (2*u+1 < NPAIR) ? (2*u+1) : (NPAIR-1);
    int i1, i2, j1, j2;
    pair_of(pa, i1, i2); pair_of(pb, j1, j2);
    const float2* A1 = S + ((size_t)i1 << 20) + ((size_t)row << 10);
    const float2* A2 = S + ((size_t)i2 << 20) + ((size_t)row << 10);
    const float2* B1 = S + ((size_t)j1 << 20) + ((size_t)row << 10);
    const float2* B2 = S + ((size_t)j2 << 20) + ((size_t)row << 10);
    float2 a[4][4], z[4][4];
    #pragma unroll
    for (int k = 0; k < 4; ++k)
        #pragma unroll
        for (int q = 0; q < 4; ++q){
            int idx = t + 64*k + 256*q;
            float2 x1 = A1[idx], y1 = A2[idx], x2 = B1[idx], y2 = B2[idx];
            float2 g1 = make_float2(x1.x*y1.x + x1.y*y1.y, x1.x*y1.y - x1.y*y1.x);
            float2 g2 = make_float2(x2.x*y2.x + x2.y*y2.y, x2.x*y2.y - x2.y*y2.x);
            a[k][q] = make_float2(g1.x - g2.y, g1.y + g2.x);
        }
    r16_fft_regs<true>(B, W, t, a, z);
    const float sc = 1.0f/1024.0f;
    float2* Up = U + ((size_t)ug << 20) + ((size_t)row << 10);
    #pragma unroll
    for (int k = 0; k < 4; ++k)
        #pragma unroll
        for (int d = 0; d < 4; ++d){
            float2 v = z[k][d];
            Up[t + 64*k + 256*d] = make_float2(v.x*sc, v.y*sc);
        }
}

// ---- pairB (col): inv col FFT, c1=|Re|,c2=|Im|, per-block lse partials ----
__global__ __launch_bounds__(256) void k_pairB(const float2* __restrict__ U,
        float2* __restrict__ lsePart, int ubase, const float2* __restrict__ Wg){
    __shared__ float2 buf[4*1024];
    __shared__ float2 W[1024];
    int tid = threadIdx.x, bx = blockIdx.x, ug = blockIdx.y;
    int cb = ((bx & 7) << 5) | (bx >> 3);
    int c0 = cb*4;
    int u = ubase + ug;
    load_W(W, Wg, tid);
    const float2* Up = U + ((size_t)ug << 20);
    for (int it = 0; it < 16; ++it){
        int rr = it*64 + (tid>>2), cc = tid & 3;
        buf[cc*1024 + SW(rr)] = Up[((size_t)rr << 10) + c0 + cc];
    }
    __syncthreads();
    int col = tid >> 6, t = tid & 63;
    float2* B = buf + col*1024;
    float2 z[4][4];
    r16_fft_lds<true>(B, W, t, z);
    const float sc = 1.0f/1024.0f;
    float m1 = -1.f, m2 = -1.f;
    #pragma unroll
    for (int k = 0; k < 4; ++k)
        #pragma unroll
        for (int d = 0; d < 4; ++d){
            float c1 = fabsf(z[k][d].x)*sc, c2 = fabsf(z[k][d].y)*sc;
            z[k][d] = make_float2(c1, c2);
            m1 = fmaxf(m1, c1); m2 = fmaxf(m2, c2);
        }
    for (int o = 32; o > 0; o >>= 1){
        m1 = fmaxf(m1, __shfl_down(m1, o, 64));
        m2 = fmaxf(m2, __shfl_down(m2, o, 64));
    }
    // stash per-wave partials in the wave's own (now dead) LDS slice
    if (t == 0) B[0] = make_float2(m1, m2);
    __syncthreads();
    float M1 = -1.f, M2 = -1.f;
    #pragma unroll
    for (int ww = 0; ww < 4; ++ww){
        float2 v = buf[ww*1024];
        M1 = fmaxf(M1, v.x); M2 = fmaxf(M2, v.y);
    }
    float s1 = 0.f, s2 = 0.f;
    #pragma unroll
    for (int k = 0; k < 4; ++k)
        #pragma unroll
        for (int d = 0; d < 4; ++d){
            s1 += expf((z[k][d].x - M1) * 100.0f);
            s2 += expf((z[k][d].y - M2) * 100.0f);
        }
    for (int o = 32; o > 0; o >>= 1){
        s1 += __shfl_down(s1, o, 64);
        s2 += __shfl_down(s2, o, 64);
    }
    if (t == 0) B[1] = make_float2(s1, s2);
    __syncthreads();
    if (tid == 0){
        float S1 = 0.f, S2 = 0.f;
        #pragma unroll
        for (int ww = 0; ww < 4; ++ww){
            float2 v = buf[ww*1024 + 1];
            S1 += v.x; S2 += v.y;
        }
        lsePart[(size_t)(2*u)*256 + cb] = make_float2(M1, S1);
        if (2*u+1 < NPAIR)
            lsePart[(size_t)(2*u+1)*256 + cb] = make_float2(M2, S2);
    }
}

// ---- final: 10 diag sums + 45 off ----
__global__ __launch_bounds__(256) void k_final(const float* __restrict__ dpart,
        const float2* __restrict__ lsePart, float* __restrict__ out){
    __shared__ double dred[4];
    __shared__ float fred[4];
    int b = blockIdx.x, tid = threadIdx.x;
    if (b < NZ){
        double s = (double)dpart[b*256 + tid];
        for (int o = 32; o > 0; o >>= 1) s += __shfl_down(s, o, 64);
        if ((tid & 63) == 0) dred[tid >> 6] = s;
        __syncthreads();
        if (tid == 0) out[b] = (float)(dred[0]+dred[1]+dred[2]+dred[3]);
    } else {
        int p = b - NZ;
        float2 v = lsePart[(size_t)p*256 + tid];
        float m = v.x;
        for (int o = 32; o > 0; o >>= 1) m = fmaxf(m, __shfl_down(m, o, 64));
        if ((tid & 63) == 0) fred[tid >> 6] = m;
        __syncthreads();
        float M = fmaxf(fmaxf(fred[0], fred[1]), fmaxf(fred[2], fred[3]));
        double s = (double)v.y * (double)expf((v.x - M)*100.0f);
        for (int o = 32; o > 0; o >>= 1) s += __shfl_down(s, o, 64);
        if ((tid & 63) == 0) dred[tid >> 6] = s;
        __syncthreads();
        if (tid == 0)
            out[NZ + p] = (float)(30.0*(double)M + 0.3*log(dred[0]+dred[1]+dred[2]+dred[3]));
    }
}

extern "C" void kernel_launch(void* const* d_in, const int* in_sizes, int n_in,
                              void* d_out, int out_size, void* d_ws, size_t ws_size,
                              hipStream_t stream){
    const float* rlist   = (const float*)d_in[0];
    const float* xpos    = (const float*)d_in[1];
    const float* ypos    = (const float*)d_in[2];
    const float* defocus = (const float*)d_in[3];
    const float* tF      = (const float*)d_in[4];
    const float* dmask   = (const float*)d_in[5];
    float* out = (float*)d_out;

    char* ws = (char*)d_ws;
    const size_t S_B = 83886080ull;          // 10 plane-FFT buffers, 80 MiB
    float2* S       = (float2*)(ws);
    char*   tail    = ws + S_B;              // 256 KiB small-buffer region
    float*  sumPart = (float*) (tail);                   // 40 KiB
    float*  dpart   = (float*) (tail + 65536);           // 10 KiB
    float2* lsePart = (float2*)(tail + 131072);          // 90 KiB
    float2* Wg      = (float2*)(tail + 229376);          // 8 KiB
    char*   X       = ws + S_B + 262144;
    float2* phiA    = (float2*)(X);                      // 8 MiB (dead after p1)
    float2* HT      = (float2*)(X + 8388608);            // 8 MiB (dead after p2)
    float2* TM      = (float2*)(X + 16777216);           // 8 MiB (dead after p4)
    float2* U       = (float2*)(X);                      // UB*8 MiB (alive in pair stage)

    size_t Xoff = S_B + 262144;
    int UB = (ws_size >= Xoff + (64ull<<20)) ? 8 : 6;

    k_prep<<<9220, 256, 0, stream>>>(rlist, xpos, ypos, tF, dmask, phiA, HT, TM, Wg);
    k_p1 <<<dim3(256, NZ), 256, 0, stream>>>(phiA, defocus, S, Wg);
    k_p2 <<<dim3(256, NZ), 256, 0, stream>>>(S, HT, Wg);
    k_p3 <<<dim3(256, NZ), 256, 0, stream>>>(S, sumPart, Wg);
    k_p4 <<<dim3(256, NZ), 256, 0, stream>>>(S, sumPart, TM, dpart, Wg);
    for (int g = 0; g < NUNIT; g += UB){
        int cnt = (NUNIT - g < UB) ? (NUNIT - g) : UB;
        k_pairA<<<dim3(256, cnt), 256, 0, stream>>>(S, U, g, Wg);
        k_pairB<<<dim3(256, cnt), 256, 0, stream>>>(U, lsePart, g, Wg);
    }
    k_final<<<NZ + NPAIR, 256, 0, stream>>>(dpart, lsePart, out);
}